// Round 8
// baseline (282.854 us; speedup 1.0000x reference)
//
#include <hip/hip_runtime.h>
#include <cstdint>

#pragma clang fp contract(off)

constexpr int cB = 16;
constexpr int cN = 22743;
constexpr int cROW = 85;
constexpr int cK = 1000;
constexpr float CONF_T = 0.5f;
constexpr float NMS_T = 0.4f;

// ---------------- kernel 1: per-row score -> orderable uint key ----------------
__global__ __launch_bounds__(256) void k_score(const float* __restrict__ in,
                                               unsigned* __restrict__ ukey) {
  __shared__ float sdata[10880];              // 128 rows x 85 floats = 43.52 KB
  constexpr int F4_PER_BLK = 2720;
  constexpr int TOTAL_F4 = (cB * cN * cROW) / 4;
  int tid = threadIdx.x;
  const float4* gin4 = (const float4*)in;
  float4* s4 = (float4*)sdata;
  int base_f4 = blockIdx.x * F4_PER_BLK;
#pragma unroll
  for (int q = 0; q < 11; ++q) {
    int k = tid + 256 * q;
    if (k < F4_PER_BLK) {
      int g = base_f4 + k;
      if (g < TOTAL_F4) s4[k] = gin4[g];
    }
  }
  __syncthreads();
  int r = tid >> 1, h = tid & 1;              // pair (2r,2r+1) -> row r
  int grow = blockIdx.x * 128 + r;
  if (grow < cB * cN) {
    const float* rowp = sdata + cROW * r;
    int j0 = 5 + h * 40;
    float m0 = rowp[j0 + 0], m1 = rowp[j0 + 1];
    float m2 = rowp[j0 + 2], m3 = rowp[j0 + 3];
#pragma unroll
    for (int k = 4; k < 40; k += 4) {
      m0 = fmaxf(m0, rowp[j0 + k + 0]);
      m1 = fmaxf(m1, rowp[j0 + k + 1]);
      m2 = fmaxf(m2, rowp[j0 + k + 2]);
      m3 = fmaxf(m3, rowp[j0 + k + 3]);
    }
    float m = fmaxf(fmaxf(m0, m1), fmaxf(m2, m3));
    m = fmaxf(m, __shfl_xor(m, 1));
    if (h == 0) {
      float obj = rowp[4];
      unsigned u = 0u;
      if (obj >= CONF_T) {
        float s = obj * m;
        if (s > 0.0f) u = __float_as_uint(s);
      }
      ukey[grow] = u;
    }
  }
}

// ---------------- bitonic sort (u32 asc; only for the rare exact-tie path) ----
__device__ __forceinline__ void sort1024_u32_asc(unsigned* a, int tid) {
  for (int k = 2; k <= 1024; k <<= 1) {
    for (int j = k >> 1; j >= 1; j >>= 1) {
      __syncthreads();
      if (tid < 512) {
        int i = ((tid & ~(j - 1)) << 1) | (tid & (j - 1));
        int p = i | j;
        unsigned x = a[i], y = a[p];
        bool up = ((i & k) == 0);
        bool sw = up ? (x > y) : (x < y);
        if (sw) { a[i] = y; a[p] = x; }
      }
    }
  }
  __syncthreads();
}

// ---------------- kernel 2: exact top-1000 per image ----------------
// All 23 ukey values per thread are loaded into REGISTERS upfront (independent
// loads, one latency exposure) and reused across hist/compact/tie passes. R7's
// version re-read global in a dependent loop body (~900 cy x 23 x 2 passes at
// 16 waves/CU -> ~30 us).
constexpr int TK_IT = (cN + 1023) / 1024;   // 23

__global__ __launch_bounds__(1024) void k_topk(const unsigned* __restrict__ ukey,
                                               int* __restrict__ topidx) {
  __shared__ unsigned hist[2048];
  __shared__ unsigned wtot[16];
  __shared__ unsigned long long cand[1024];
  __shared__ unsigned eqbuf[1024];
  __shared__ unsigned sh_T, sh_newrank, sh_E, sh_cnt;
  int img = blockIdx.x;
  int tid = threadIdx.x;
  int lane = tid & 63;
  int wv = tid >> 6;
  const unsigned* uk = ukey + (size_t)img * cN;

  unsigned uv[TK_IT];
#pragma unroll
  for (int q = 0; q < TK_IT; ++q) {
    int i = q * 1024 + tid;
    uv[q] = (i < cN) ? uk[i] : 0u;
  }

  unsigned prefix = 0;
  int bits = 0;
  unsigned rank = cK;
  unsigned gtc = 0;
  unsigned E = 0;

  for (int r = 0; r < 3; ++r) {
    int nb = (r < 2) ? 11 : 10;
    int shift = 32 - bits - nb;
    unsigned bmask = (1u << nb) - 1u;
    hist[tid] = 0u; hist[tid + 1024] = 0u;
    __syncthreads();
#pragma unroll
    for (int q = 0; q < TK_IT; ++q) {
      int i = q * 1024 + tid;
      unsigned u = uv[q];
      bool match = (i < cN) && (bits == 0 || (u >> (32 - bits)) == prefix);
      bool isz = match && (u == 0u);
      bool nz = match && (u != 0u);
      unsigned long long mz = __ballot(isz);
      if (isz && lane == (__ffsll((long long)mz) - 1))
        atomicAdd(&hist[0], (unsigned)__popcll(mz));
      if (nz) atomicAdd(&hist[(u >> shift) & bmask], 1u);
    }
    __syncthreads();
    // hierarchical suffix scan over 2048 bins (3 barriers)
    unsigned h0 = hist[2 * tid];
    unsigned h1 = hist[2 * tid + 1];
    unsigned s2 = h0 + h1;
#pragma unroll
    for (int s = 1; s < 64; s <<= 1) {
      unsigned t = __shfl_down(s2, s);
      s2 += (lane + s < 64) ? t : 0u;
    }
    if (lane == 0) wtot[wv] = s2;
    __syncthreads();
    unsigned above = 0;
    for (int w2 = wv + 1; w2 < 16; ++w2) above += wtot[w2];
    unsigned S_even = above + s2;
    unsigned S_odd = S_even - h0;
    unsigned S_next = S_odd - h1;
    if (S_even >= rank && S_odd < rank) { sh_T = 2u * tid; sh_newrank = rank - S_odd; sh_E = h0; }
    if (S_odd >= rank && S_next < rank) { sh_T = 2u * tid + 1u; sh_newrank = rank - S_next; sh_E = h1; }
    __syncthreads();
    unsigned T = sh_T;
    unsigned nr = sh_newrank;
    E = sh_E;
    gtc += rank - nr;
    rank = nr;
    prefix = (prefix << nb) | T;
    bits += nb;
    __syncthreads();
    if (gtc + E <= 1024u) break;
  }

  bool tiepath = (gtc + E > 1024u);
  unsigned pivotLo = (bits >= 32) ? prefix : (prefix << (32 - bits));
  cand[tid] = (unsigned long long)tid;   // distinct filler keys, high32 = 0
  eqbuf[tid] = 0xFFFFFFFFu;
  if (tid == 0) sh_cnt = 0u;
  __syncthreads();

  if (!tiepath) {
#pragma unroll
    for (int q = 0; q < TK_IT; ++q) {
      int i = q * 1024 + tid;
      unsigned u = uv[q];
      bool m = (i < cN) && (u >= pivotLo);
      unsigned long long mb = __ballot(m);
      if (m) {
        int ldr = __ffsll((long long)mb) - 1;
        unsigned base = 0;
        if (lane == ldr) base = atomicAdd(&sh_cnt, (unsigned)__popcll(mb));
        base = __shfl(base, ldr);
        unsigned pos = base + (unsigned)__popcll(mb & ((1ull << lane) - 1ull));
        if (pos < 1024u)
          cand[pos] = ((unsigned long long)u << 32) |
                      (unsigned long long)(0xFFFFFFFFu - (unsigned)i);
      }
    }
    __syncthreads();
  } else {
    unsigned P = prefix;
    for (int q = 0; q < TK_IT; ++q) {
      int i = q * 1024 + tid;
      unsigned u = uv[q];
      bool gt = (i < cN) && (u > P);
      unsigned long long mb = __ballot(gt);
      if (gt) {
        int ldr = __ffsll((long long)mb) - 1;
        unsigned base = 0;
        if (lane == ldr) base = atomicAdd(&sh_cnt, (unsigned)__popcll(mb));
        base = __shfl(base, ldr);
        unsigned pos = base + (unsigned)__popcll(mb & ((1ull << lane) - 1ull));
        if (pos < 1024u)
          cand[pos] = ((unsigned long long)u << 32) |
                      (unsigned long long)(0xFFFFFFFFu - (unsigned)i);
      }
    }
    __syncthreads();
    if (tid == 0) sh_E = 0u;
    __syncthreads();
    for (int q = 0; q < TK_IT; ++q) {
      int i = q * 1024 + tid;
      unsigned u = uv[q];
      bool eq = (i < cN) && (u == P);
      unsigned long long mb = __ballot(eq);
      if (eq) {
        int ldr = __ffsll((long long)mb) - 1;
        unsigned base = 0;
        if (lane == ldr) base = atomicAdd(&sh_E, (unsigned)__popcll(mb));
        base = __shfl(base, ldr);
        unsigned pos = base + (unsigned)__popcll(mb & ((1ull << lane) - 1ull));
        if (pos < 1024u) eqbuf[pos] = (unsigned)i;
      }
    }
    __syncthreads();
    sort1024_u32_asc(eqbuf, tid);
    int need = (int)cK - (int)gtc;
    for (int t = tid; t < need; t += 1024) {
      unsigned idx = eqbuf[t];
      if (idx != 0xFFFFFFFFu)
        cand[gtc + (unsigned)t] = ((unsigned long long)P << 32) |
                                  (unsigned long long)(0xFFFFFFFFu - idx);
    }
    __syncthreads();
  }

  // rank-by-count: distinct keys -> rank is a permutation of 0..1023
  unsigned long long my = cand[tid];
  unsigned rk = 0;
#pragma unroll 8
  for (int j = 0; j < 1024; ++j) rk += (cand[j] > my) ? 1u : 0u;
  if (rk < (unsigned)cK) {
    unsigned uhi = (unsigned)(my >> 32);
    int idx = (int)(0xFFFFFFFFu - (unsigned)(my & 0xFFFFFFFFull));
    topidx[img * cK + (int)rk] = (uhi > 0u) ? idx : -1;
  }
}

// ---------------- kernel 3: gather ----------------
__global__ __launch_bounds__(256) void k_gather(const float* __restrict__ in,
                                                const int* __restrict__ topidx,
                                                float4* __restrict__ boxes,
                                                float* __restrict__ area,
                                                float* __restrict__ objv,
                                                float* __restrict__ confv,
                                                int* __restrict__ clsv,
                                                int* __restrict__ validv) {
  int wid = (int)((blockIdx.x * 256u + threadIdx.x) >> 6);
  int lane = threadIdx.x & 63;
  if (wid >= cB * cK) return;
  int img = wid / cK;
  int idx = topidx[wid];
  if (idx < 0) {
    if (lane == 0) {
      boxes[wid] = make_float4(0.f, 0.f, 0.f, 0.f);
      area[wid] = 0.f; objv[wid] = 0.f; confv[wid] = 0.f;
      clsv[wid] = -1; validv[wid] = 0;
    }
    return;
  }
  const float* row = in + ((size_t)img * cN + (size_t)idx) * cROW;
  float v = row[5 + lane];
  int ci = lane;
  if (lane < 16) {
    float v2 = row[69 + lane];
    if (v2 > v) { v = v2; ci = 64 + lane; }
  }
#pragma unroll
  for (int m = 1; m < 64; m <<= 1) {
    float ov = __shfl_xor(v, m);
    int oc = __shfl_xor(ci, m);
    if (ov > v || (ov == v && oc < ci)) { v = ov; ci = oc; }
  }
  if (lane == 0) {
    float cx = row[0], cy = row[1], w = row[2], h = row[3], ob = row[4];
    float hw = w * 0.5f, hh = h * 0.5f;
    float x1 = cx - hw, y1 = cy - hh, x2 = cx + hw, y2 = cy + hh;
    boxes[wid] = make_float4(x1, y1, x2, y2);
    area[wid] = fmaxf(x2 - x1, 0.f) * fmaxf(y2 - y1, 0.f);
    objv[wid] = ob; confv[wid] = v; clsv[wid] = ci; validv[wid] = 1;
  }
}

// ---------------- kernel 4: suppress bitmask, TRANSPOSED output ----------------
// Ballot-transposed access: lanes read CONSECUTIVE j (j = 32*blk + w), the 32
// suppress bits of word blk are collected with one __ballot (low/high half =
// the wave's two rows); LDS packed as float4 box + float2 (area, cls). 2 wide
// conflict-free LDS reads per iteration vs R7's 6 scalar ones (192 -> 64).
__global__ __launch_bounds__(256) void k_suppress(const float4* __restrict__ boxes,
                                                  const float* __restrict__ area,
                                                  const int* __restrict__ clsv,
                                                  unsigned* __restrict__ St) {
  __shared__ float4 sbox[1024];
  __shared__ float2 sac[1024];          // x = area, y = cls (int bits)
  int img = blockIdx.x >> 7;            // / 128
  int rb = (blockIdx.x & 127) * 8;      // 8 rows per block
  int tid = threadIdx.x;
  for (int i = tid; i < 1024; i += 256) {
    if (i < cK) {
      sbox[i] = boxes[img * cK + i];
      float2 t;
      t.x = area[img * cK + i];
      t.y = __int_as_float(clsv[img * cK + i]);
      sac[i] = t;
    } else {
      sbox[i] = make_float4(0.f, 0.f, 0.f, 0.f);
      float2 t; t.x = 0.f; t.y = __int_as_float(-2);
      sac[i] = t;
    }
  }
  __syncthreads();
  int i = rb + (tid >> 5);              // row (wave64 = 2 rows x 32 w-lanes)
  int w = tid & 31;
  float4 bb = sbox[i];                  // broadcast within 32-lane group
  float2 bac = sac[i];
  float ba = bac.x;
  int bc = __float_as_int(bac.y);
  unsigned word = 0u;
#pragma unroll 8
  for (int blk = 0; blk < 32; ++blk) {
    int j = (blk << 5) | w;             // consecutive across lanes
    float4 jb = sbox[j];
    float2 ja = sac[j];
    float xx1 = fmaxf(bb.x, jb.x);
    float yy1 = fmaxf(bb.y, jb.y);
    float xx2 = fminf(bb.z, jb.z);
    float yy2 = fminf(bb.w, jb.w);
    float inter = fmaxf(xx2 - xx1, 0.f) * fmaxf(yy2 - yy1, 0.f);
    float uni = ba + ja.x - inter;
    float iou = inter / (uni + 1e-16f);
    bool sup = (iou > NMS_T) && (bc == __float_as_int(ja.y));
    unsigned long long mk = __ballot(sup);
    if (blk == w) word = (tid & 32) ? (unsigned)(mk >> 32) : (unsigned)mk;
  }
  St[((size_t)(img * 32 + w)) * 1024 + (size_t)i] = word;
}

// ---------------- kernel 5: word-batched greedy NMS + masked write ----------------
__device__ __forceinline__ unsigned u4c(const uint4& v, int c) {
  return c == 0 ? v.x : c == 1 ? v.y : c == 2 ? v.z : v.w;
}

__device__ __forceinline__ void nms_load(const uint4* __restrict__ colv, int b,
                                         uint4 (&buf)[8]) {
#pragma unroll
  for (int q = 0; q < 8; ++q) buf[q] = colv[8 * b + q];
}

__device__ __forceinline__ void nms_proc(int b, int lane, unsigned& kw,
                                         const uint4 (&W)[8]) {
  unsigned dec = 0u;
  if (lane == b) {
    unsigned kwb = kw;
#pragma unroll
    for (int t = 0; t < 32; ++t) {
      if ((kwb >> t) & 1u) {
        dec |= (1u << t);
        unsigned rw = u4c(W[t >> 2], t & 3);
        unsigned mgt = (t == 31) ? 0u : (0xFFFFFFFFu << (t + 1));
        kwb &= ~(rw & mgt);
      }
    }
    kw = kwb;
  }
  dec = __shfl(dec, b);
  if (lane > b) {
#pragma unroll
    for (int t = 0; t < 32; ++t) {
      unsigned sel = 0u - ((dec >> t) & 1u);
      kw &= ~(u4c(W[t >> 2], t & 3) & sel);
    }
  }
}

__global__ __launch_bounds__(64) void k_nms(const unsigned* __restrict__ St,
                                            const int* __restrict__ validv,
                                            const float4* __restrict__ boxes,
                                            const float* __restrict__ objv,
                                            const float* __restrict__ confv,
                                            const int* __restrict__ clsv,
                                            float* __restrict__ out) {
  __shared__ unsigned keep_sh[32];
  int img = blockIdx.x;
  int lane = threadIdx.x;
  if (lane < 32) {
    const uint4* colv = (const uint4*)(St + ((size_t)(img * 32 + lane)) * 1024);
    unsigned kw = 0u;
    for (int b = 0; b < 32; ++b) {
      int k = (lane << 5) + b;
      if (k < cK && validv[img * cK + k]) kw |= (1u << b);
    }
    uint4 bufA[8], bufB[8];
    nms_load(colv, 0, bufA);
    for (int b = 0; b < 32; b += 2) {
      if (b + 1 < 32) nms_load(colv, b + 1, bufB);
      nms_proc(b, lane, kw, bufA);
      if (b + 2 < 32) nms_load(colv, b + 2, bufA);
      nms_proc(b + 1, lane, kw, bufB);
    }
    keep_sh[lane] = kw;
  }
  __syncthreads();
  for (int k = lane; k < cK; k += 64) {
    bool kp = ((keep_sh[k >> 5] >> (k & 31)) & 1u) != 0u;
    size_t o = ((size_t)img * cK + (size_t)k) * 7;
    if (kp) {
      float4 b = boxes[img * cK + k];
      out[o + 0] = b.x; out[o + 1] = b.y; out[o + 2] = b.z; out[o + 3] = b.w;
      out[o + 4] = objv[img * cK + k];
      out[o + 5] = confv[img * cK + k];
      out[o + 6] = (float)clsv[img * cK + k];
    } else {
      out[o + 0] = 0.f; out[o + 1] = 0.f; out[o + 2] = 0.f; out[o + 3] = 0.f;
      out[o + 4] = 0.f; out[o + 5] = 0.f; out[o + 6] = 0.f;
    }
  }
}

extern "C" void kernel_launch(void* const* d_in, const int* in_sizes, int n_in,
                              void* d_out, int out_size, void* d_ws, size_t ws_size,
                              hipStream_t stream) {
  const float* in = (const float*)d_in[0];
  float* out = (float*)d_out;
  char* ws = (char*)d_ws;
  size_t off = 0;
  auto take = [&](size_t bytes) {
    size_t r = off;
    off += (bytes + 255) & ~(size_t)255;
    return r;
  };
  unsigned* ukey = (unsigned*)(ws + take((size_t)cB * cN * 4));
  int* topidx = (int*)(ws + take((size_t)cB * cK * 4));
  float4* boxes = (float4*)(ws + take((size_t)cB * cK * 16));
  float* area = (float*)(ws + take((size_t)cB * cK * 4));
  float* objv = (float*)(ws + take((size_t)cB * cK * 4));
  float* confv = (float*)(ws + take((size_t)cB * cK * 4));
  int* clsv = (int*)(ws + take((size_t)cB * cK * 4));
  int* validv = (int*)(ws + take((size_t)cB * cK * 4));
  unsigned* St = (unsigned*)(ws + take((size_t)cB * 32 * 1024 * 4));

  int nrows = cB * cN;
  int blocks1 = (nrows + 127) / 128;
  k_score<<<blocks1, 256, 0, stream>>>(in, ukey);
  k_topk<<<cB, 1024, 0, stream>>>(ukey, topidx);
  int waves3 = cB * cK;
  k_gather<<<(waves3 * 64 + 255) / 256, 256, 0, stream>>>(in, topidx, boxes, area,
                                                          objv, confv, clsv, validv);
  k_suppress<<<cB * 128, 256, 0, stream>>>(boxes, area, clsv, St);
  k_nms<<<cB, 64, 0, stream>>>(St, validv, boxes, objv, confv, clsv, out);
}